// Round 10
// baseline (552.131 us; speedup 1.0000x reference)
//
#include <hip/hip_runtime.h>
#include <hip/hip_bf16.h>

#define IN_DIM  128
#define HID_DIM 128
#define OUT_DIM 64
#define BCAP    1536       // edges per 64-node bucket (mean 1024, +16 sigma)
#define RSTRIDE 64         // pack row stride (slots per node; deg<=64 w.p. ~1)

typedef unsigned short ushort_t;
struct ushort4_t { ushort_t x, y, z, w; };
typedef __attribute__((ext_vector_type(8))) short bf16x8;   // 8 bf16 (4 VGPRs)
typedef __attribute__((ext_vector_type(4))) float f32x4;    // MFMA acc

__device__ __forceinline__ float bf2f(ushort_t u) {
    return __uint_as_float(((unsigned int)u) << 16);
}
__device__ __forceinline__ short f2bf_s(float v) {
    __hip_bfloat16 t = __float2bfloat16(v);
    return *(short*)&t;
}
__device__ __forceinline__ unsigned int pack2(float a, float b) {
    return ((unsigned int)(ushort_t)f2bf_s(b) << 16) | (ushort_t)f2bf_s(a);
}
// two bf16 packed in one u32 -> two f32 (shift for lo, AND for hi)
__device__ __forceinline__ void bf2x(unsigned int u, float& lo, float& hi) {
    lo = __uint_as_float(u << 16);
    hi = __uint_as_float(u & 0xffff0000u);
}

// ---------------- phase 1: scatter edges into dst-range buckets ----------------
// Hot per-bucket cursors (1563 counters) instead of 100k scattered counters:
// atomic line-ops become line-local -> off the random-line-op wall.
__global__ void edge_bucket(const int* __restrict__ src, const int* __restrict__ dst,
                            int E, int* __restrict__ cursor, unsigned int* __restrict__ ebuf) {
    int e = blockIdx.x * blockDim.x + threadIdx.x;
    if (e < E) {
        int d = dst[e];
        int b = d >> 6;
        int pos = atomicAdd(&cursor[b], 1);
        if (pos < BCAP)
            ebuf[(size_t)b * BCAP + pos] = ((unsigned int)src[e] << 6) | (unsigned int)(d & 63);
    }
}

// ---------------- phase 2: per-bucket rank + CSR fill + degree + dinv ----------------
// Degree is bucket-local (bucket == exact dst range) -> no global scan needed.
// pack rows are fixed stride RSTRIDE; pad slots left as garbage (masked in gather).
__global__ void bucket_build(const int* __restrict__ cursor, const unsigned int* __restrict__ ebuf,
                             unsigned int* __restrict__ pack, int* __restrict__ cnt,
                             float* __restrict__ dinv, int N) {
    __shared__ int c64[64];
    const int b = blockIdx.x;
    const int t = threadIdx.x;
    if (t < 64) c64[t] = 0;
    __syncthreads();
    int nb = cursor[b]; if (nb > BCAP) nb = BCAP;
    const unsigned int* eb = ebuf + (size_t)b * BCAP;
    for (int i = t; i < nb; i += 256) {
        unsigned int rec = eb[i];
        int local = rec & 63;
        unsigned int s = rec >> 6;
        int rk = atomicAdd(&c64[local], 1);      // LDS atomic: rank within node
        if (rk < RSTRIDE)
            pack[((size_t)(b * 64 + local)) * RSTRIDE + rk] = s;
    }
    __syncthreads();
    if (t < 64) {
        int node = b * 64 + t;
        if (node < N) {
            int c = c64[t]; if (c > RSTRIDE) c = RSTRIDE;
            cnt[node] = c;
            dinv[node] = rsqrtf((float)(c + 1));  // +1 self loop
        }
    }
}

// ---------------- GEMM1 (MFMA): h1[N,128](bf16) = x[N,128] @ W1[128,128] ----------------
// D = W1^T·x^T per 16-node tile; 4 waves/block, persistent grid-stride.
__global__ __launch_bounds__(256, 2) void gemm1_mfma(
        const float* __restrict__ x, const float* __restrict__ W,
        unsigned int* __restrict__ h, int N, int NT, int NW) {
    const int tid  = threadIdx.x;
    const int lane = tid & 63;
    const int m    = lane & 15;
    const int quad = lane >> 4;
    const int gw   = blockIdx.x * 4 + (tid >> 6);

    bf16x8 a[8][4];                         // 8 col-tiles x 4 k-chunks
    #pragma unroll
    for (int ct = 0; ct < 8; ++ct)
        #pragma unroll
        for (int kc = 0; kc < 4; ++kc)
            #pragma unroll
            for (int j = 0; j < 8; ++j)
                a[ct][kc][j] = f2bf_s(W[(size_t)(kc * 32 + quad * 8 + j) * HID_DIM + ct * 16 + m]);

    for (int t = gw; t < NT; t += NW) {
        const int n0 = t * 16;
        int node = n0 + m; if (node >= N) node = N - 1;
        const float* xr = x + (size_t)node * IN_DIM + quad * 8;
        f32x4 acc[8];
        #pragma unroll
        for (int ct = 0; ct < 8; ++ct) acc[ct] = (f32x4){0.f, 0.f, 0.f, 0.f};
        #pragma unroll
        for (int kc = 0; kc < 4; ++kc) {
            const float4 v0 = *(const float4*)(xr + kc * 32);
            const float4 v1 = *(const float4*)(xr + kc * 32 + 4);
            bf16x8 b;
            b[0] = f2bf_s(v0.x); b[1] = f2bf_s(v0.y); b[2] = f2bf_s(v0.z); b[3] = f2bf_s(v0.w);
            b[4] = f2bf_s(v1.x); b[5] = f2bf_s(v1.y); b[6] = f2bf_s(v1.z); b[7] = f2bf_s(v1.w);
            #pragma unroll
            for (int ct = 0; ct < 8; ++ct)
                acc[ct] = __builtin_amdgcn_mfma_f32_16x16x32_bf16(a[ct][kc], b, acc[ct], 0, 0, 0);
        }
        if (n0 + m < N) {
            unsigned int* o = h + (size_t)(n0 + m) * (HID_DIM / 2) + quad * 2;
            #pragma unroll
            for (int ct = 0; ct < 8; ++ct) {
                uint2 pv;
                pv.x = pack2(acc[ct][0], acc[ct][1]);
                pv.y = pack2(acc[ct][2], acc[ct][3]);
                *(uint2*)(o + ct * 8) = pv;
            }
        }
    }
}

// ---------------- GEMM2 (MFMA): h2[N,64](bf16) = relu(agg(bf16) + b1) @ W2[128,64] ----
__global__ __launch_bounds__(256) void gemm2_mfma(
        const ushort_t* __restrict__ agg, const float* __restrict__ b1,
        const float* __restrict__ W2, unsigned int* __restrict__ h2,
        int N, int NT, int NW) {
    const int tid  = threadIdx.x;
    const int lane = tid & 63;
    const int m    = lane & 15;
    const int quad = lane >> 4;
    const int gw   = blockIdx.x * 4 + (tid >> 6);

    bf16x8 a[4][4];
    #pragma unroll
    for (int ct = 0; ct < 4; ++ct)
        #pragma unroll
        for (int kc = 0; kc < 4; ++kc)
            #pragma unroll
            for (int j = 0; j < 8; ++j)
                a[ct][kc][j] = f2bf_s(W2[(size_t)(kc * 32 + quad * 8 + j) * OUT_DIM + ct * 16 + m]);

    float4 b1v[8];
    #pragma unroll
    for (int kc = 0; kc < 4; ++kc) {
        b1v[kc * 2]     = *(const float4*)(b1 + kc * 32 + quad * 8);
        b1v[kc * 2 + 1] = *(const float4*)(b1 + kc * 32 + quad * 8 + 4);
    }

    for (int t = gw; t < NT; t += NW) {
        const int n0 = t * 16;
        int node = n0 + m; if (node >= N) node = N - 1;
        const ushort_t* ar = agg + (size_t)node * HID_DIM + quad * 8;
        f32x4 acc[4];
        #pragma unroll
        for (int ct = 0; ct < 4; ++ct) acc[ct] = (f32x4){0.f, 0.f, 0.f, 0.f};
        #pragma unroll
        for (int kc = 0; kc < 4; ++kc) {
            const ushort4_t r0 = *(const ushort4_t*)(ar + kc * 32);
            const ushort4_t r1 = *(const ushort4_t*)(ar + kc * 32 + 4);
            const float4 ba = b1v[kc * 2], bb = b1v[kc * 2 + 1];
            bf16x8 b;
            b[0] = f2bf_s(fmaxf(bf2f(r0.x) + ba.x, 0.f));
            b[1] = f2bf_s(fmaxf(bf2f(r0.y) + ba.y, 0.f));
            b[2] = f2bf_s(fmaxf(bf2f(r0.z) + ba.z, 0.f));
            b[3] = f2bf_s(fmaxf(bf2f(r0.w) + ba.w, 0.f));
            b[4] = f2bf_s(fmaxf(bf2f(r1.x) + bb.x, 0.f));
            b[5] = f2bf_s(fmaxf(bf2f(r1.y) + bb.y, 0.f));
            b[6] = f2bf_s(fmaxf(bf2f(r1.z) + bb.z, 0.f));
            b[7] = f2bf_s(fmaxf(bf2f(r1.w) + bb.w, 0.f));
            #pragma unroll
            for (int ct = 0; ct < 4; ++ct)
                acc[ct] = __builtin_amdgcn_mfma_f32_16x16x32_bf16(a[ct][kc], b, acc[ct], 0, 0, 0);
        }
        if (n0 + m < N) {
            unsigned int* o = h2 + (size_t)(n0 + m) * (OUT_DIM / 2) + quad * 2;
            #pragma unroll
            for (int ct = 0; ct < 4; ++ct) {
                uint2 pv;
                pv.x = pack2(acc[ct][0], acc[ct][1]);
                pv.y = pack2(acc[ct][2], acc[ct][3]);
                *(uint2*)(o + ct * 8) = pv;
            }
        }
    }
}

// ---------------- gather: bf16 messages, 4B src records, norm from dinv in-kernel ----
// TPN = D/8 lanes per node, uint4 (8 bf16) per lane. Pack rows stride RSTRIDE;
// tail/garbage slots masked by (e+i < cnt) selects (s falls back to own node, n=0).
template<int D, bool BF16_OUT>
__global__ void gather_bf16(const ushort_t* __restrict__ h, const unsigned int* __restrict__ pack,
                            const int* __restrict__ cnt, const float* __restrict__ dinv,
                            const float* __restrict__ bias, int N, void* __restrict__ outv) {
    const int TPN = D / 8;
    const int NPB = 256 / TPN;
    const int t = threadIdx.x;
    const int node = blockIdx.x * NPB + t / TPN;
    if (node >= N) return;
    const int f = (t & (TPN - 1)) * 8;
    const float dd = dinv[node];

    float acc[8];
    {
        const uint4 su = *(const uint4*)(h + (size_t)node * D + f);
        const float sn = dd * dd;
        float l, hi2;
        bf2x(su.x, l, hi2); acc[0] = l * sn; acc[1] = hi2 * sn;
        bf2x(su.y, l, hi2); acc[2] = l * sn; acc[3] = hi2 * sn;
        bf2x(su.z, l, hi2); acc[4] = l * sn; acc[5] = hi2 * sn;
        bf2x(su.w, l, hi2); acc[6] = l * sn; acc[7] = hi2 * sn;
    }
    if (bias) {
        const float4 b0 = *(const float4*)(bias + f);
        const float4 b1 = *(const float4*)(bias + f + 4);
        acc[0] += b0.x; acc[1] += b0.y; acc[2] += b0.z; acc[3] += b0.w;
        acc[4] += b1.x; acc[5] += b1.y; acc[6] += b1.z; acc[7] += b1.w;
    }

    const unsigned int* pk = pack + (size_t)node * RSTRIDE;   // 256B-aligned row
    const int c    = cnt[node];
    const int cpad = (c + 7) & ~7;
    for (int e = 0; e < cpad; e += 8) {
        const uint4 r0 = *(const uint4*)(pk + e);
        const uint4 r1 = *(const uint4*)(pk + e + 4);
        int   si[8];
        float ni[8];
        si[0] = r0.x; si[1] = r0.y; si[2] = r0.z; si[3] = r0.w;
        si[4] = r1.x; si[5] = r1.y; si[6] = r1.z; si[7] = r1.w;
        #pragma unroll
        for (int i = 0; i < 8; ++i) {
            const bool ok = (e + i) < c;
            const int s = ok ? si[i] : node;        // garbage slot -> own (hot) row
            si[i] = s;
            ni[i] = ok ? dinv[s] * dd : 0.0f;       // broadcast-coalesced 4B load
        }
        uint4 v[8];
        #pragma unroll
        for (int i = 0; i < 8; ++i)
            v[i] = *(const uint4*)(h + (size_t)si[i] * D + f);
        #pragma unroll
        for (int i = 0; i < 8; ++i) {
            float l, hi2;
            bf2x(v[i].x, l, hi2); acc[0] += l * ni[i]; acc[1] += hi2 * ni[i];
            bf2x(v[i].y, l, hi2); acc[2] += l * ni[i]; acc[3] += hi2 * ni[i];
            bf2x(v[i].z, l, hi2); acc[4] += l * ni[i]; acc[5] += hi2 * ni[i];
            bf2x(v[i].w, l, hi2); acc[6] += l * ni[i]; acc[7] += hi2 * ni[i];
        }
    }
    if (BF16_OUT) {
        unsigned int* out = (unsigned int*)outv;
        uint4 pv;
        pv.x = pack2(acc[0], acc[1]);
        pv.y = pack2(acc[2], acc[3]);
        pv.z = pack2(acc[4], acc[5]);
        pv.w = pack2(acc[6], acc[7]);
        *(uint4*)(out + ((size_t)node * D + f) / 2) = pv;
    } else {
        float* out = (float*)outv;
        float4 o0 = {acc[0], acc[1], acc[2], acc[3]};
        float4 o1 = {acc[4], acc[5], acc[6], acc[7]};
        *(float4*)(out + (size_t)node * D + f)     = o0;
        *(float4*)(out + (size_t)node * D + f + 4) = o1;
    }
}

extern "C" void kernel_launch(void* const* d_in, const int* in_sizes, int n_in,
                              void* d_out, int out_size, void* d_ws, size_t ws_size,
                              hipStream_t stream) {
    const float* x   = (const float*)d_in[0];
    const int*   ei  = (const int*)  d_in[1];
    const float* W1  = (const float*)d_in[2];
    const float* b1  = (const float*)d_in[3];
    const float* W2  = (const float*)d_in[4];
    const float* b2  = (const float*)d_in[5];
    float* out = (float*)d_out;

    const int N = in_sizes[0] / IN_DIM;     // 100000
    const int E = in_sizes[1] / 2;          // 1600000
    const int* src = ei;                    // edge_index[0]
    const int* dst = ei + E;                // edge_index[1]

    const int NB  = (N + 63) >> 6;          // 64-node buckets (1563)
    const int NB4 = (NB + 3) & ~3;          // padded for alignment

    // workspace (4B units):
    // cursor[NB4] | cnt[N] | dinv[N] f32 | ebuf[NB*BCAP] u32 | pack[NB*64*RSTRIDE] u32
    // | h1[N*64] u32 (bf16, reused as h2) | agg1[N*64] u32 (bf16)
    int*   cursor = (int*)d_ws;
    int*   cnt    = cursor + NB4;
    float* dinv   = (float*)(cnt + N);
    unsigned int* ebuf = (unsigned int*)(dinv + N);
    unsigned int* pack = ebuf + (size_t)NB * BCAP;
    unsigned int* h1   = pack + (size_t)NB * 64 * RSTRIDE;
    unsigned int* agg1 = h1 + (size_t)N * (HID_DIM / 2);
    unsigned int* h2   = h1;                // reuse after gather128

    const int B = 256;
    const int NT = (N + 15) / 16;           // 16-node MFMA tiles

    // 1) CSR build: bucket scatter (hot cursors) + per-bucket rank/fill/degree
    hipMemsetAsync(cursor, 0, (size_t)NB4 * sizeof(int), stream);
    edge_bucket<<<(E + B - 1) / B, B, 0, stream>>>(src, dst, E, cursor, ebuf);
    bucket_build<<<NB, 256, 0, stream>>>(cursor, ebuf, pack, cnt, dinv, N);

    // 2) h1 = x @ W1  (bf16 out, MFMA)
    gemm1_mfma<<<512, 256, 0, stream>>>(x, W1, h1, N, NT, 512 * 4);

    // 3) agg1 = gather(h1)  (bf16 out)
    gather_bf16<HID_DIM, true><<<(N + 15) / 16, 256, 0, stream>>>(
        (const ushort_t*)h1, pack, cnt, dinv, nullptr, N, (void*)agg1);

    // 4) h2 = relu(agg1 + b1) @ W2  (bf16 out, MFMA)
    gemm2_mfma<<<768, 256, 0, stream>>>(
        (const ushort_t*)agg1, b1, W2, h2, N, NT, 768 * 4);

    // 5) out = b2 + gather(h2)  (f32 out)
    gather_bf16<OUT_DIM, false><<<(N + 31) / 32, 256, 0, stream>>>(
        (const ushort_t*)h2, pack, cnt, dinv, b2, N, (void*)out);
}

// Round 11
// 348.811 us; speedup vs baseline: 1.5829x; 1.5829x over previous
//
#include <hip/hip_runtime.h>
#include <hip/hip_bf16.h>

#define IN_DIM  128
#define HID_DIM 128
#define OUT_DIM 64
#define RSTRIDE 64         // slots per node row; P(deg>64)~1e-19 for Poisson(16)
#define CFB     1024       // count_fill blocks in fused kernel
#define G1B     512        // gemm1 blocks in fused kernel

typedef unsigned short ushort_t;
struct ushort4_t { ushort_t x, y, z, w; };
typedef __attribute__((ext_vector_type(8))) short bf16x8;   // 8 bf16 (4 VGPRs)
typedef __attribute__((ext_vector_type(4))) float f32x4;    // MFMA acc

__device__ __forceinline__ float bf2f(ushort_t u) {
    return __uint_as_float(((unsigned int)u) << 16);
}
__device__ __forceinline__ short f2bf_s(float v) {
    __hip_bfloat16 t = __float2bfloat16(v);
    return *(short*)&t;
}
__device__ __forceinline__ unsigned int pack2(float a, float b) {
    return ((unsigned int)(ushort_t)f2bf_s(b) << 16) | (ushort_t)f2bf_s(a);
}
// two bf16 packed in one u32 -> two f32 (shift for lo, AND for hi)
__device__ __forceinline__ void bf2x(unsigned int u, float& lo, float& hi) {
    lo = __uint_as_float(u << 16);
    hi = __uint_as_float(u & 0xffff0000u);
}

// ---------------- fused: count+fill (blocks < CFB) + gemm1 MFMA (blocks >= CFB) ----
// count_fill: one pass. rk = atomicAdd(cnt[d]); pack[d*64+rk] = src.
//   No scans, no rank array, no pack zeroing (garbage masked by cnt in gather).
// gemm1: h1[N,128](bf16) = x[N,128] @ W1[128,128], D = W1^T·x^T per 16-node tile.
__global__ __launch_bounds__(256) void fused_countfill_gemm1(
        const int* __restrict__ src, const int* __restrict__ dst, int E,
        int* __restrict__ cnt, unsigned int* __restrict__ pack,
        const float* __restrict__ x, const float* __restrict__ W,
        unsigned int* __restrict__ h, int N, int NT) {
    const int tid = threadIdx.x;
    if (blockIdx.x < CFB) {
        // ---- count + fill role (grid-stride over edges) ----
        const int stride = CFB * 256;
        for (int e = blockIdx.x * 256 + tid; e < E; e += stride) {
            int d = dst[e];
            int rk = atomicAdd(&cnt[d], 1);
            if (rk < RSTRIDE)
                pack[(size_t)d * RSTRIDE + rk] = (unsigned int)src[e];
        }
    } else {
        // ---- gemm1 role ----
        const int lane = tid & 63;
        const int m    = lane & 15;
        const int quad = lane >> 4;
        const int gw   = (blockIdx.x - CFB) * 4 + (tid >> 6);
        const int NW   = G1B * 4;

        bf16x8 a[8][4];                     // 8 col-tiles x 4 k-chunks
        #pragma unroll
        for (int ct = 0; ct < 8; ++ct)
            #pragma unroll
            for (int kc = 0; kc < 4; ++kc)
                #pragma unroll
                for (int j = 0; j < 8; ++j)
                    a[ct][kc][j] = f2bf_s(W[(size_t)(kc * 32 + quad * 8 + j) * HID_DIM + ct * 16 + m]);

        for (int t = gw; t < NT; t += NW) {
            const int n0 = t * 16;
            int node = n0 + m; if (node >= N) node = N - 1;
            const float* xr = x + (size_t)node * IN_DIM + quad * 8;
            f32x4 acc[8];
            #pragma unroll
            for (int ct = 0; ct < 8; ++ct) acc[ct] = (f32x4){0.f, 0.f, 0.f, 0.f};
            #pragma unroll
            for (int kc = 0; kc < 4; ++kc) {
                const float4 v0 = *(const float4*)(xr + kc * 32);
                const float4 v1 = *(const float4*)(xr + kc * 32 + 4);
                bf16x8 b;
                b[0] = f2bf_s(v0.x); b[1] = f2bf_s(v0.y); b[2] = f2bf_s(v0.z); b[3] = f2bf_s(v0.w);
                b[4] = f2bf_s(v1.x); b[5] = f2bf_s(v1.y); b[6] = f2bf_s(v1.z); b[7] = f2bf_s(v1.w);
                #pragma unroll
                for (int ct = 0; ct < 8; ++ct)
                    acc[ct] = __builtin_amdgcn_mfma_f32_16x16x32_bf16(a[ct][kc], b, acc[ct], 0, 0, 0);
            }
            if (n0 + m < N) {
                unsigned int* o = h + (size_t)(n0 + m) * (HID_DIM / 2) + quad * 2;
                #pragma unroll
                for (int ct = 0; ct < 8; ++ct) {
                    uint2 pv;
                    pv.x = pack2(acc[ct][0], acc[ct][1]);
                    pv.y = pack2(acc[ct][2], acc[ct][3]);
                    *(uint2*)(o + ct * 8) = pv;
                }
            }
        }
    }
}

// ---------------- dinv from counts ----------------
__global__ void make_dinv(const int* __restrict__ cnt, float* __restrict__ dinv, int N) {
    int i = blockIdx.x * blockDim.x + threadIdx.x;
    if (i < N) dinv[i] = rsqrtf((float)(cnt[i] + 1));  // +1 self loop
}

// ---------------- GEMM2 (MFMA): h2[N,64](bf16) = relu(agg(bf16) + b1) @ W2[128,64] ----
__global__ __launch_bounds__(256) void gemm2_mfma(
        const ushort_t* __restrict__ agg, const float* __restrict__ b1,
        const float* __restrict__ W2, unsigned int* __restrict__ h2,
        int N, int NT, int NW) {
    const int tid  = threadIdx.x;
    const int lane = tid & 63;
    const int m    = lane & 15;
    const int quad = lane >> 4;
    const int gw   = blockIdx.x * 4 + (tid >> 6);

    bf16x8 a[4][4];
    #pragma unroll
    for (int ct = 0; ct < 4; ++ct)
        #pragma unroll
        for (int kc = 0; kc < 4; ++kc)
            #pragma unroll
            for (int j = 0; j < 8; ++j)
                a[ct][kc][j] = f2bf_s(W2[(size_t)(kc * 32 + quad * 8 + j) * OUT_DIM + ct * 16 + m]);

    float4 b1v[8];
    #pragma unroll
    for (int kc = 0; kc < 4; ++kc) {
        b1v[kc * 2]     = *(const float4*)(b1 + kc * 32 + quad * 8);
        b1v[kc * 2 + 1] = *(const float4*)(b1 + kc * 32 + quad * 8 + 4);
    }

    for (int t = gw; t < NT; t += NW) {
        const int n0 = t * 16;
        int node = n0 + m; if (node >= N) node = N - 1;
        const ushort_t* ar = agg + (size_t)node * HID_DIM + quad * 8;
        f32x4 acc[4];
        #pragma unroll
        for (int ct = 0; ct < 4; ++ct) acc[ct] = (f32x4){0.f, 0.f, 0.f, 0.f};
        #pragma unroll
        for (int kc = 0; kc < 4; ++kc) {
            const ushort4_t r0 = *(const ushort4_t*)(ar + kc * 32);
            const ushort4_t r1 = *(const ushort4_t*)(ar + kc * 32 + 4);
            const float4 ba = b1v[kc * 2], bb = b1v[kc * 2 + 1];
            bf16x8 b;
            b[0] = f2bf_s(fmaxf(bf2f(r0.x) + ba.x, 0.f));
            b[1] = f2bf_s(fmaxf(bf2f(r0.y) + ba.y, 0.f));
            b[2] = f2bf_s(fmaxf(bf2f(r0.z) + ba.z, 0.f));
            b[3] = f2bf_s(fmaxf(bf2f(r0.w) + ba.w, 0.f));
            b[4] = f2bf_s(fmaxf(bf2f(r1.x) + bb.x, 0.f));
            b[5] = f2bf_s(fmaxf(bf2f(r1.y) + bb.y, 0.f));
            b[6] = f2bf_s(fmaxf(bf2f(r1.z) + bb.z, 0.f));
            b[7] = f2bf_s(fmaxf(bf2f(r1.w) + bb.w, 0.f));
            #pragma unroll
            for (int ct = 0; ct < 4; ++ct)
                acc[ct] = __builtin_amdgcn_mfma_f32_16x16x32_bf16(a[ct][kc], b, acc[ct], 0, 0, 0);
        }
        if (n0 + m < N) {
            unsigned int* o = h2 + (size_t)(n0 + m) * (OUT_DIM / 2) + quad * 2;
            #pragma unroll
            for (int ct = 0; ct < 4; ++ct) {
                uint2 pv;
                pv.x = pack2(acc[ct][0], acc[ct][1]);
                pv.y = pack2(acc[ct][2], acc[ct][3]);
                *(uint2*)(o + ct * 8) = pv;
            }
        }
    }
}

// ---------------- gather: bf16 messages, 4B src records, norm from dinv in-kernel ----
// TPN = D/8 lanes per node, uint4 (8 bf16) per lane. Pack rows stride RSTRIDE;
// garbage slots (rank >= cnt) masked by (e+i < c) BEFORE any use of the record.
template<int D, bool BF16_OUT>
__global__ void gather_bf16(const ushort_t* __restrict__ h, const unsigned int* __restrict__ pack,
                            const int* __restrict__ cnt, const float* __restrict__ dinv,
                            const float* __restrict__ bias, int N, void* __restrict__ outv) {
    const int TPN = D / 8;
    const int NPB = 256 / TPN;
    const int t = threadIdx.x;
    const int node = blockIdx.x * NPB + t / TPN;
    if (node >= N) return;
    const int f = (t & (TPN - 1)) * 8;
    const float dd = dinv[node];

    float acc[8];
    {
        const uint4 su = *(const uint4*)(h + (size_t)node * D + f);
        const float sn = dd * dd;
        float l, hi2;
        bf2x(su.x, l, hi2); acc[0] = l * sn; acc[1] = hi2 * sn;
        bf2x(su.y, l, hi2); acc[2] = l * sn; acc[3] = hi2 * sn;
        bf2x(su.z, l, hi2); acc[4] = l * sn; acc[5] = hi2 * sn;
        bf2x(su.w, l, hi2); acc[6] = l * sn; acc[7] = hi2 * sn;
    }
    if (bias) {
        const float4 b0 = *(const float4*)(bias + f);
        const float4 b1 = *(const float4*)(bias + f + 4);
        acc[0] += b0.x; acc[1] += b0.y; acc[2] += b0.z; acc[3] += b0.w;
        acc[4] += b1.x; acc[5] += b1.y; acc[6] += b1.z; acc[7] += b1.w;
    }

    const unsigned int* pk = pack + (size_t)node * RSTRIDE;   // 256B-aligned row
    int c = cnt[node]; if (c > RSTRIDE) c = RSTRIDE;
    const int cpad = (c + 7) & ~7;
    for (int e = 0; e < cpad; e += 8) {
        const uint4 r0 = *(const uint4*)(pk + e);
        const uint4 r1 = *(const uint4*)(pk + e + 4);
        int   si[8];
        float ni[8];
        si[0] = r0.x; si[1] = r0.y; si[2] = r0.z; si[3] = r0.w;
        si[4] = r1.x; si[5] = r1.y; si[6] = r1.z; si[7] = r1.w;
        #pragma unroll
        for (int i = 0; i < 8; ++i) {
            const bool ok = (e + i) < c;
            const int s = ok ? si[i] : node;        // garbage slot -> own (hot) row
            si[i] = s;
            ni[i] = ok ? dinv[s] * dd : 0.0f;       // dinv is 400KB, L2-resident
        }
        uint4 v[8];
        #pragma unroll
        for (int i = 0; i < 8; ++i)
            v[i] = *(const uint4*)(h + (size_t)si[i] * D + f);
        #pragma unroll
        for (int i = 0; i < 8; ++i) {
            float l, hi2;
            bf2x(v[i].x, l, hi2); acc[0] += l * ni[i]; acc[1] += hi2 * ni[i];
            bf2x(v[i].y, l, hi2); acc[2] += l * ni[i]; acc[3] += hi2 * ni[i];
            bf2x(v[i].z, l, hi2); acc[4] += l * ni[i]; acc[5] += hi2 * ni[i];
            bf2x(v[i].w, l, hi2); acc[6] += l * ni[i]; acc[7] += hi2 * ni[i];
        }
    }
    if (BF16_OUT) {
        unsigned int* out = (unsigned int*)outv;
        uint4 pv;
        pv.x = pack2(acc[0], acc[1]);
        pv.y = pack2(acc[2], acc[3]);
        pv.z = pack2(acc[4], acc[5]);
        pv.w = pack2(acc[6], acc[7]);
        *(uint4*)(out + ((size_t)node * D + f) / 2) = pv;
    } else {
        float* out = (float*)outv;
        float4 o0 = {acc[0], acc[1], acc[2], acc[3]};
        float4 o1 = {acc[4], acc[5], acc[6], acc[7]};
        *(float4*)(out + (size_t)node * D + f)     = o0;
        *(float4*)(out + (size_t)node * D + f + 4) = o1;
    }
}

extern "C" void kernel_launch(void* const* d_in, const int* in_sizes, int n_in,
                              void* d_out, int out_size, void* d_ws, size_t ws_size,
                              hipStream_t stream) {
    const float* x   = (const float*)d_in[0];
    const int*   ei  = (const int*)  d_in[1];
    const float* W1  = (const float*)d_in[2];
    const float* b1  = (const float*)d_in[3];
    const float* W2  = (const float*)d_in[4];
    const float* b2  = (const float*)d_in[5];
    float* out = (float*)d_out;

    const int N = in_sizes[0] / IN_DIM;     // 100000
    const int E = in_sizes[1] / 2;          // 1600000
    const int* src = ei;                    // edge_index[0]
    const int* dst = ei + E;                // edge_index[1]

    // workspace (4B units):
    // cnt[N] | dinv[N] f32 | pack[N*RSTRIDE] u32 | h1[N*64] u32 (bf16, reused as h2)
    // | agg1[N*64] u32 (bf16)
    int*   cnt  = (int*)d_ws;
    float* dinv = (float*)(cnt + N);
    unsigned int* pack = (unsigned int*)(dinv + N);
    unsigned int* h1   = pack + (size_t)N * RSTRIDE;
    unsigned int* agg1 = h1 + (size_t)N * (HID_DIM / 2);
    unsigned int* h2   = h1;                // reuse after gather128

    const int B = 256;
    const int NT = (N + 15) / 16;           // 16-node MFMA tiles

    // 1) zero counters (400 KB), then single-pass count+fill fused with gemm1
    hipMemsetAsync(cnt, 0, (size_t)N * sizeof(int), stream);
    fused_countfill_gemm1<<<CFB + G1B, B, 0, stream>>>(
        src, dst, E, cnt, pack, x, W1, h1, N, NT);
    make_dinv<<<(N + B - 1) / B, B, 0, stream>>>(cnt, dinv, N);

    // 2) agg1 = gather(h1)  (bf16 out)
    gather_bf16<HID_DIM, true><<<(N + 15) / 16, B, 0, stream>>>(
        (const ushort_t*)h1, pack, cnt, dinv, nullptr, N, (void*)agg1);

    // 3) h2 = relu(agg1 + b1) @ W2  (bf16 out, MFMA)
    gemm2_mfma<<<768, B, 0, stream>>>(
        (const ushort_t*)agg1, b1, W2, h2, N, NT, 768 * 4);

    // 4) out = b2 + gather(h2)  (f32 out)
    gather_bf16<OUT_DIM, false><<<(N + 31) / 32, B, 0, stream>>>(
        (const ushort_t*)h2, pack, cnt, dinv, b2, N, (void*)out);
}